// Round 5
// baseline (217.159 us; speedup 1.0000x reference)
//
#include <hip/hip_runtime.h>
#include <hip/hip_bf16.h>

typedef __bf16 bf16;
typedef __bf16 bf16x4 __attribute__((ext_vector_type(4)));
typedef __bf16 bf16x8 __attribute__((ext_vector_type(8)));
typedef float  f32x4  __attribute__((ext_vector_type(4)));

#define NEG_INF (-1e9f)
#define N_SCENES 2048

// ---------------------------------------------------------------------------
// Prep: block 0: exclusive prefix sum of agents + counting sort of scenes by
// nb descending (perm[]); blocks 1..64: fp32 -> bf16 weight conversion.
// ---------------------------------------------------------------------------
__global__ __launch_bounds__(256) void prep_kernel(
    const float* __restrict__ w_in, const float* __restrict__ w_out,
    const int* __restrict__ agents,
    bf16* __restrict__ w_in_b, bf16* __restrict__ w_out_b,
    int* __restrict__ offs, int* __restrict__ perm)
{
    __shared__ int tot[256];
    __shared__ int cnt[65];
    __shared__ int start[65];
    const int t = threadIdx.x;
    if (blockIdx.x == 0) {
        if (t < 65) cnt[t] = 0;
        int loc[8]; int s = 0;
        #pragma unroll
        for (int j = 0; j < 8; ++j) { loc[j] = agents[t * 8 + j]; s += loc[j]; }
        tot[t] = s;
        __syncthreads();                    // also covers cnt init
        for (int o = 1; o < 256; o <<= 1) {
            int v = (t >= o) ? tot[t - o] : 0;
            __syncthreads();
            tot[t] += v;
            __syncthreads();
        }
        int run = tot[t] - s;
        #pragma unroll
        for (int j = 0; j < 8; ++j) { offs[t * 8 + j] = run; run += loc[j]; }
        // histogram of nb
        #pragma unroll
        for (int j = 0; j < 8; ++j) atomicAdd(&cnt[loc[j]], 1);
        __syncthreads();
        if (t == 0) {                       // descending bin starts
            int pos = 0;
            for (int v = 64; v >= 1; --v) { start[v] = pos; pos += cnt[v]; }
        }
        __syncthreads();
        #pragma unroll
        for (int j = 0; j < 8; ++j) {
            int p = atomicAdd(&start[loc[j]], 1);
            perm[p] = t * 8 + j;
        }
    } else {
        int i = (blockIdx.x - 1) * 1024 + t * 4;
        float4 v; bf16* dst;
        if (i < 49152) { v = *(const float4*)(w_in + i);            dst = w_in_b + i; }
        else           { v = *(const float4*)(w_out + (i - 49152)); dst = w_out_b + (i - 49152); }
        bf16x4 o = { (bf16)v.x, (bf16)v.y, (bf16)v.z, (bf16)v.w };
        *(bf16x4*)dst = o;
    }
}

// ---------------------------------------------------------------------------
// R5: all-register fused attention. One block (4 waves) per scene (scenes
// sorted by nb desc via perm); wave w owns head w. Q/K/P/ctx fragments are
// produced by in-register quad-shuffle transforms (HW-validated in R4);
// only vT round-trips through a per-wave 4KB LDS buffer, which is then
// reused for the cross-head ctx exchange. LDS = 16KB/block; target
// 4 blocks/CU via __launch_bounds__(256,4) (<=128 unified VGPRs).
// MFMA 16x16x32_bf16: A[m=lane&15][k=quad*8+jj], B[k=quad*8+jj][n=lane&15],
// C/D: col=lane&15, row=quad*4+reg.
// Universal C->frag transform (two row-stacked 16x16 C-tiles T0,T1):
//   frag[jj] = select(qd<2, shfl(T0[jj&3], sl), shfl(T1[jj&3], sl)),
//   sl = r + (qd&1)*32 + (jj>>2)*16.
// ---------------------------------------------------------------------------
__global__ __launch_bounds__(256, 4) void attn_kernel(
    const float* __restrict__ att_in,
    const float* __restrict__ b_in, const float* __restrict__ b_out,
    const bf16* __restrict__ w_in_b, const bf16* __restrict__ w_out_b,
    const int* __restrict__ agents, const int* __restrict__ offs,
    const int* __restrict__ perm, float* __restrict__ out)
{
    __shared__ bf16 s_lds[4 * 2048];   // 16 KB: per-wave vT[32][64] then ctxS

    const int b     = blockIdx.x;
    const int tid   = threadIdx.x;
    const int lane  = tid & 63;
    const int w     = tid >> 6;        // wave id == head id
    const int h     = w;
    const int r     = lane & 15;
    const int qd    = lane >> 4;       // quad 0..3
    const int q1    = qd & 1;
    const int qh    = qd >> 1;
    const int scene = perm[b];
    const int nb    = agents[scene];
    const int off   = offs[scene];
    const int mtc   = (nb + 15) >> 4;  // live m-tiles (1..4)

    bf16* mylds = s_lds + w * 2048;    // vT[32][64] (stage1/2), ctxS (stage2/3)

    // ---- zero-fill output rows [nb, 64) ----
    {
        const float4 z4 = make_float4(0.f, 0.f, 0.f, 0.f);
        const int nz = (64 - nb) * 32;
        for (int i = tid; i < nz; i += 256) {
            int row = nb + (i >> 5);
            *(float4*)(out + ((size_t)scene * 64 + row) * 128 + (i & 31) * 4) = z4;
        }
    }

    // ---- zero vT units for agents >= mtc*16 (keep PV inputs finite) ----
    {
        bf16x4 z4 = {(bf16)0.f,(bf16)0.f,(bf16)0.f,(bf16)0.f};
        int zrow = lane >> 1, zh = lane & 1;     // 32 rows x 2 halves
        #pragma unroll
        for (int u = 2; u < 8; ++u)
            if (u >= 2 * mtc) {
                int uu = u ^ (zrow & 7);
                *(bf16x4*)(mylds + zrow * 64 + uu * 8 + zh * 4) = z4;
            }
    }

    // ---- stage 1: per mt-pair, compute Q,K (reg frags via shuffle) and V(LDS)
    bf16x8 qB[4], kA[4];               // only mt < mtc entries are consumed
    #pragma unroll
    for (int pr = 0; pr < 2; ++pr)
        if (pr * 2 < mtc) {
            // x fragments for the pair (rows >= nb -> 0)
            bf16x8 xa[2][4];
            #pragma unroll
            for (int ms = 0; ms < 2; ++ms) {
                const int mt = pr * 2 + ms;
                const int xrow = mt * 16 + r;
                const bool vr = xrow < nb;
                const float* px = att_in + (((size_t)(off + xrow)) << 7) + qd * 8;
                #pragma unroll
                for (int ks = 0; ks < 4; ++ks) {
                    float4 lo = make_float4(0.f,0.f,0.f,0.f), hi = lo;
                    if (vr) {
                        lo = *(const float4*)(px + ks * 32);
                        hi = *(const float4*)(px + ks * 32 + 4);
                    }
                    xa[ms][ks] = (bf16x8){(bf16)lo.x,(bf16)lo.y,(bf16)lo.z,(bf16)lo.w,
                                          (bf16)hi.x,(bf16)hi.y,(bf16)hi.z,(bf16)hi.w};
                }
            }
            // Q (kind 0) and K (kind 1): C-tiles then shuffle -> frags
            #pragma unroll
            for (int kind = 0; kind < 2; ++kind) {
                f32x4 C[2][2];                     // [ms][jt]
                #pragma unroll
                for (int jt = 0; jt < 2; ++jt) {
                    const int j0 = kind * 128 + h * 32 + jt * 16;
                    const bf16* pw = w_in_b + (size_t)(j0 + r) * 128 + qd * 8;
                    bf16x8 wb[4];
                    #pragma unroll
                    for (int ks = 0; ks < 4; ++ks)
                        wb[ks] = *(const bf16x8*)(pw + ks * 32);
                    const float4 b4 = *(const float4*)(b_in + j0 + qd * 4);
                    #pragma unroll
                    for (int ms = 0; ms < 2; ++ms) {
                        f32x4 acc = {0.f,0.f,0.f,0.f};
                        #pragma unroll
                        for (int ks = 0; ks < 4; ++ks)
                            acc = __builtin_amdgcn_mfma_f32_16x16x32_bf16(wb[ks], xa[ms][ks], acc, 0, 0, 0);
                        acc[0] += b4.x; acc[1] += b4.y; acc[2] += b4.z; acc[3] += b4.w;
                        C[ms][jt] = acc;
                    }
                }
                #pragma unroll
                for (int ms = 0; ms < 2; ++ms) {
                    const int mt = pr * 2 + ms;
                    float tv[8];
                    #pragma unroll
                    for (int jj = 0; jj < 8; ++jj) {
                        int sl = r + q1 * 32 + (jj >> 2) * 16;
                        float f0 = __shfl(C[ms][0][jj & 3], sl);
                        float f1 = __shfl(C[ms][1][jj & 3], sl);
                        tv[jj] = (qd < 2) ? f0 : f1;
                    }
                    bf16x8 fr = {(bf16)tv[0],(bf16)tv[1],(bf16)tv[2],(bf16)tv[3],
                                 (bf16)tv[4],(bf16)tv[5],(bf16)tv[6],(bf16)tv[7]};
                    if (kind == 0) qB[mt] = fr; else kA[mt] = fr;
                }
            }
            // V: C-tiles -> packed vT LDS writes
            #pragma unroll
            for (int jt = 0; jt < 2; ++jt) {
                const int j0 = 256 + h * 32 + jt * 16;
                const bf16* pw = w_in_b + (size_t)(j0 + r) * 128 + qd * 8;
                bf16x8 wb[4];
                #pragma unroll
                for (int ks = 0; ks < 4; ++ks)
                    wb[ks] = *(const bf16x8*)(pw + ks * 32);
                const float bv = b_in[j0 + r];
                #pragma unroll
                for (int ms = 0; ms < 2; ++ms) {
                    const int mt = pr * 2 + ms;
                    if (mt < mtc) {
                        f32x4 acc = {0.f,0.f,0.f,0.f};
                        #pragma unroll
                        for (int ks = 0; ks < 4; ++ks)
                            acc = __builtin_amdgcn_mfma_f32_16x16x32_bf16(xa[ms][ks], wb[ks], acc, 0, 0, 0);
                        const int rowd = jt * 16 + r;
                        const int uu = (mt * 2 + qh) ^ (rowd & 7);
                        bf16x4 pk = {(bf16)(acc[0]+bv), (bf16)(acc[1]+bv),
                                     (bf16)(acc[2]+bv), (bf16)(acc[3]+bv)};
                        *(bf16x4*)(mylds + rowd * 64 + uu * 8 + q1 * 4) = pk;
                    }
                }
            }
        }

    // ---- preload V^T A-frags (wave-private LDS, no barrier needed) ----
    bf16x8 vf[2][2];
    #pragma unroll
    for (int dt = 0; dt < 2; ++dt)
        #pragma unroll
        for (int hk = 0; hk < 2; ++hk) {
            int row = dt * 16 + r;
            vf[dt][hk] = *(const bf16x8*)(mylds + row * 64 + ((hk * 4 + qd) ^ (row & 7)) * 8);
        }

    const float scale = 0.17677669529663687f;    // 1/sqrt(32)
    const int hkc = (mtc + 1) >> 1;

    // ---- stage 2: per query-tile: S^T -> softmax -> P^T(shuffle) -> PV ----
    #pragma unroll
    for (int mt = 0; mt < 4; ++mt)
        if (mt < mtc) {
            f32x4 S[4];
            #pragma unroll
            for (int nt = 0; nt < 4; ++nt)
                if (nt < mtc) {
                    f32x4 z = {0.f,0.f,0.f,0.f};
                    S[nt] = __builtin_amdgcn_mfma_f32_16x16x32_bf16(kA[nt], qB[mt], z, 0, 0, 0);
                }
            // masked softmax over keys n = nt*16 + qd*4 + i (cross-quad reduce)
            float mx = NEG_INF;
            #pragma unroll
            for (int nt = 0; nt < 4; ++nt) {
                if (nt < mtc) {
                    #pragma unroll
                    for (int i = 0; i < 4; ++i) {
                        bool kv = (nt * 16 + qd * 4 + i) < nb;
                        float val = kv ? S[nt][i] * scale : NEG_INF;
                        S[nt][i] = val;
                        mx = fmaxf(mx, val);
                    }
                } else {
                    S[nt] = (f32x4){NEG_INF, NEG_INF, NEG_INF, NEG_INF};
                }
            }
            mx = fmaxf(mx, __shfl_xor(mx, 16));
            mx = fmaxf(mx, __shfl_xor(mx, 32));
            float l = 0.f;
            #pragma unroll
            for (int nt = 0; nt < 4; ++nt)
                #pragma unroll
                for (int i = 0; i < 4; ++i) {
                    float e = __expf(S[nt][i] - mx);
                    S[nt][i] = e; l += e;
                }
            l += __shfl_xor(l, 16);
            l += __shfl_xor(l, 32);
            const float rl = 1.0f / l;
            #pragma unroll
            for (int nt = 0; nt < 4; ++nt)
                #pragma unroll
                for (int i = 0; i < 4; ++i)
                    S[nt][i] *= rl;                       // invalid keys -> exact 0

            // PV: O^T = V^T * P^T ; P^T frag via quad-shuffle from S^T C-tiles
            f32x4 o0 = {0.f,0.f,0.f,0.f}, o1 = {0.f,0.f,0.f,0.f};
            #pragma unroll
            for (int hk = 0; hk < 2; ++hk)
                if (hk < hkc) {
                    float pv[8];
                    #pragma unroll
                    for (int jj = 0; jj < 8; ++jj) {
                        int sl = r + q1 * 32 + (jj >> 2) * 16;
                        float f0 = __shfl(S[2*hk  ][jj & 3], sl);
                        float f1 = __shfl(S[2*hk+1][jj & 3], sl);
                        pv[jj] = (qd < 2) ? f0 : f1;
                    }
                    bf16x8 pf = {(bf16)pv[0],(bf16)pv[1],(bf16)pv[2],(bf16)pv[3],
                                 (bf16)pv[4],(bf16)pv[5],(bf16)pv[6],(bf16)pv[7]};
                    o0 = __builtin_amdgcn_mfma_f32_16x16x32_bf16(vf[0][hk], pf, o0, 0, 0, 0);
                    o1 = __builtin_amdgcn_mfma_f32_16x16x32_bf16(vf[1][hk], pf, o1, 0, 0, 0);
                }

            // ctx^T B-frag via quad-shuffle -> one b128 write (overlays vT)
            float cv[8];
            #pragma unroll
            for (int jj = 0; jj < 8; ++jj) {
                int sl = r + q1 * 32 + (jj >> 2) * 16;
                float f0 = __shfl(o0[jj & 3], sl);
                float f1 = __shfl(o1[jj & 3], sl);
                cv[jj] = (qd < 2) ? f0 : f1;
            }
            bf16x8 cf = {(bf16)cv[0],(bf16)cv[1],(bf16)cv[2],(bf16)cv[3],
                         (bf16)cv[4],(bf16)cv[5],(bf16)cv[6],(bf16)cv[7]};
            *(bf16x8*)(mylds + mt * 512 + lane * 8) = cf;
        }

    // ---- stage 3 weights (issue before barrier to overlap the wait) ----
    bf16x8 wof[2][4]; float4 bo4[2];
    #pragma unroll
    for (int t2 = 0; t2 < 2; ++t2) {
        const int jg = (w * 2 + t2) * 16;
        const bf16* pw = w_out_b + (size_t)(jg + r) * 128 + qd * 8;
        #pragma unroll
        for (int s = 0; s < 4; ++s)
            wof[t2][s] = *(const bf16x8*)(pw + s * 32);
        bo4[t2] = *(const float4*)(b_out + jg + qd * 4);
    }
    __syncthreads();

    // ---- stage 3: out^T = W_out * ctx^T ; float4 stores ----
    #pragma unroll
    for (int mt = 0; mt < 4; ++mt)
        if (mt < mtc) {
            bf16x8 cb[4];
            #pragma unroll
            for (int s = 0; s < 4; ++s)
                cb[s] = *(const bf16x8*)(s_lds + s * 2048 + mt * 512 + lane * 8);
            const int rowa = mt * 16 + r;
            #pragma unroll
            for (int t2 = 0; t2 < 2; ++t2) {
                f32x4 acc = {0.f,0.f,0.f,0.f};
                #pragma unroll
                for (int s = 0; s < 4; ++s)
                    acc = __builtin_amdgcn_mfma_f32_16x16x32_bf16(wof[t2][s], cb[s], acc, 0, 0, 0);
                if (rowa < nb) {
                    float4 o4 = make_float4(acc[0] + bo4[t2].x, acc[1] + bo4[t2].y,
                                            acc[2] + bo4[t2].z, acc[3] + bo4[t2].w);
                    *(float4*)(out + ((size_t)scene * 64 + rowa) * 128
                               + (w * 2 + t2) * 16 + qd * 4) = o4;
                }
            }
        }
}

extern "C" void kernel_launch(void* const* d_in, const int* in_sizes, int n_in,
                              void* d_out, int out_size, void* d_ws, size_t ws_size,
                              hipStream_t stream)
{
    const float* att_in = (const float*)d_in[0];
    const float* w_in   = (const float*)d_in[1];
    const float* b_in   = (const float*)d_in[2];
    const float* w_out  = (const float*)d_in[3];
    const float* b_out  = (const float*)d_in[4];
    const int*   agents = (const int*)d_in[5];

    bf16* w_in_b  = (bf16*)d_ws;                          // 49152 * 2B
    bf16* w_out_b = w_in_b + 49152;                       // 16384 * 2B
    int*  offs    = (int*)((char*)d_ws + 131072);         // 2048 * 4B
    int*  perm    = (int*)((char*)d_ws + 131072 + 8192);  // 2048 * 4B

    prep_kernel<<<65, 256, 0, stream>>>(w_in, w_out, agents, w_in_b, w_out_b, offs, perm);
    attn_kernel<<<N_SCENES, 256, 0, stream>>>(att_in, b_in, b_out, w_in_b, w_out_b,
                                              agents, offs, perm, (float*)d_out);
}

// Round 6
// 184.267 us; speedup vs baseline: 1.1785x; 1.1785x over previous
//
#include <hip/hip_runtime.h>
#include <hip/hip_bf16.h>

typedef __bf16 bf16;
typedef __bf16 bf16x4 __attribute__((ext_vector_type(4)));
typedef __bf16 bf16x8 __attribute__((ext_vector_type(8)));
typedef float  f32x4  __attribute__((ext_vector_type(4)));

#define NEG_INF (-1e9f)
#define N_SCENES 2048

// ---------------------------------------------------------------------------
// Prep: block 0: exclusive prefix sum of agents + counting sort of scenes by
// nb descending (perm[]); blocks 1..64: fp32 -> bf16 weight conversion.
// ---------------------------------------------------------------------------
__global__ __launch_bounds__(256) void prep_kernel(
    const float* __restrict__ w_in, const float* __restrict__ w_out,
    const int* __restrict__ agents,
    bf16* __restrict__ w_in_b, bf16* __restrict__ w_out_b,
    int* __restrict__ offs, int* __restrict__ perm)
{
    __shared__ int tot[256];
    __shared__ int cnt[65];
    __shared__ int start[65];
    const int t = threadIdx.x;
    if (blockIdx.x == 0) {
        if (t < 65) cnt[t] = 0;
        int loc[8]; int s = 0;
        #pragma unroll
        for (int j = 0; j < 8; ++j) { loc[j] = agents[t * 8 + j]; s += loc[j]; }
        tot[t] = s;
        __syncthreads();                    // also covers cnt init
        for (int o = 1; o < 256; o <<= 1) {
            int v = (t >= o) ? tot[t - o] : 0;
            __syncthreads();
            tot[t] += v;
            __syncthreads();
        }
        int run = tot[t] - s;
        #pragma unroll
        for (int j = 0; j < 8; ++j) { offs[t * 8 + j] = run; run += loc[j]; }
        // histogram of nb
        #pragma unroll
        for (int j = 0; j < 8; ++j) atomicAdd(&cnt[loc[j]], 1);
        __syncthreads();
        if (t == 0) {                       // descending bin starts
            int pos = 0;
            for (int v = 64; v >= 1; --v) { start[v] = pos; pos += cnt[v]; }
        }
        __syncthreads();
        #pragma unroll
        for (int j = 0; j < 8; ++j) {
            int p = atomicAdd(&start[loc[j]], 1);
            perm[p] = t * 8 + j;
        }
    } else {
        int i = (blockIdx.x - 1) * 1024 + t * 4;
        float4 v; bf16* dst;
        if (i < 49152) { v = *(const float4*)(w_in + i);            dst = w_in_b + i; }
        else           { v = *(const float4*)(w_out + (i - 49152)); dst = w_out_b + (i - 49152); }
        bf16x4 o = { (bf16)v.x, (bf16)v.y, (bf16)v.z, (bf16)v.w };
        *(bf16x4*)dst = o;
    }
}

// ---------------------------------------------------------------------------
// R6: identical to R5 except __launch_bounds__(256, 3): R5's (256,4) forced
// VGPR_Count=64 and spilled ~140 MB/dispatch to scratch (FETCH 17.6->64.7 MB,
// WRITE 65.5->155 MB). (256,3) allows ~170 unified regs -> no spills, while
// 16 KB LDS keeps occupancy VGPR-limited at ~3 blocks/CU (vs R4's LDS-limited
// 1.85). All-register dataflow: Q/K/P/ctx frags via in-register quad-shuffle
// transforms; only vT round-trips LDS (4KB/wave), reused for ctx exchange.
// MFMA 16x16x32_bf16: A[m=lane&15][k=quad*8+jj], B[k=quad*8+jj][n=lane&15],
// C/D: col=lane&15, row=quad*4+reg.
// C->frag transform (two row-stacked 16x16 C-tiles T0,T1):
//   frag[jj] = select(qd<2, shfl(T0[jj&3], sl), shfl(T1[jj&3], sl)),
//   sl = r + (qd&1)*32 + (jj>>2)*16.
// ---------------------------------------------------------------------------
__global__ __launch_bounds__(256, 3) void attn_kernel(
    const float* __restrict__ att_in,
    const float* __restrict__ b_in, const float* __restrict__ b_out,
    const bf16* __restrict__ w_in_b, const bf16* __restrict__ w_out_b,
    const int* __restrict__ agents, const int* __restrict__ offs,
    const int* __restrict__ perm, float* __restrict__ out)
{
    __shared__ bf16 s_lds[4 * 2048];   // 16 KB: per-wave vT[32][64] then ctxS

    const int b     = blockIdx.x;
    const int tid   = threadIdx.x;
    const int lane  = tid & 63;
    const int w     = tid >> 6;        // wave id == head id
    const int h     = w;
    const int r     = lane & 15;
    const int qd    = lane >> 4;       // quad 0..3
    const int q1    = qd & 1;
    const int qh    = qd >> 1;
    const int scene = perm[b];
    const int nb    = agents[scene];
    const int off   = offs[scene];
    const int mtc   = (nb + 15) >> 4;  // live m-tiles (1..4)

    bf16* mylds = s_lds + w * 2048;    // vT[32][64] (stage1/2), ctxS (stage2/3)

    // ---- zero-fill output rows [nb, 64) ----
    {
        const float4 z4 = make_float4(0.f, 0.f, 0.f, 0.f);
        const int nz = (64 - nb) * 32;
        for (int i = tid; i < nz; i += 256) {
            int row = nb + (i >> 5);
            *(float4*)(out + ((size_t)scene * 64 + row) * 128 + (i & 31) * 4) = z4;
        }
    }

    // ---- zero vT units for agents >= mtc*16 (keep PV inputs finite) ----
    {
        bf16x4 z4 = {(bf16)0.f,(bf16)0.f,(bf16)0.f,(bf16)0.f};
        int zrow = lane >> 1, zh = lane & 1;     // 32 rows x 2 halves
        #pragma unroll
        for (int u = 2; u < 8; ++u)
            if (u >= 2 * mtc) {
                int uu = u ^ (zrow & 7);
                *(bf16x4*)(mylds + zrow * 64 + uu * 8 + zh * 4) = z4;
            }
    }

    // ---- stage 1: per mt-pair, compute Q,K (reg frags via shuffle) and V(LDS)
    bf16x8 qB[4], kA[4];               // only mt < mtc entries are consumed
    #pragma unroll
    for (int pr = 0; pr < 2; ++pr)
        if (pr * 2 < mtc) {
            // x fragments for the pair (rows >= nb -> 0)
            bf16x8 xa[2][4];
            #pragma unroll
            for (int ms = 0; ms < 2; ++ms) {
                const int mt = pr * 2 + ms;
                const int xrow = mt * 16 + r;
                const bool vr = xrow < nb;
                const float* px = att_in + (((size_t)(off + xrow)) << 7) + qd * 8;
                #pragma unroll
                for (int ks = 0; ks < 4; ++ks) {
                    float4 lo = make_float4(0.f,0.f,0.f,0.f), hi = lo;
                    if (vr) {
                        lo = *(const float4*)(px + ks * 32);
                        hi = *(const float4*)(px + ks * 32 + 4);
                    }
                    xa[ms][ks] = (bf16x8){(bf16)lo.x,(bf16)lo.y,(bf16)lo.z,(bf16)lo.w,
                                          (bf16)hi.x,(bf16)hi.y,(bf16)hi.z,(bf16)hi.w};
                }
            }
            // Q (kind 0) and K (kind 1): C-tiles then shuffle -> frags
            #pragma unroll
            for (int kind = 0; kind < 2; ++kind) {
                f32x4 C[2][2];                     // [ms][jt]
                #pragma unroll
                for (int jt = 0; jt < 2; ++jt) {
                    const int j0 = kind * 128 + h * 32 + jt * 16;
                    const bf16* pw = w_in_b + (size_t)(j0 + r) * 128 + qd * 8;
                    bf16x8 wb[4];
                    #pragma unroll
                    for (int ks = 0; ks < 4; ++ks)
                        wb[ks] = *(const bf16x8*)(pw + ks * 32);
                    const float4 b4 = *(const float4*)(b_in + j0 + qd * 4);
                    #pragma unroll
                    for (int ms = 0; ms < 2; ++ms) {
                        f32x4 acc = {0.f,0.f,0.f,0.f};
                        #pragma unroll
                        for (int ks = 0; ks < 4; ++ks)
                            acc = __builtin_amdgcn_mfma_f32_16x16x32_bf16(wb[ks], xa[ms][ks], acc, 0, 0, 0);
                        acc[0] += b4.x; acc[1] += b4.y; acc[2] += b4.z; acc[3] += b4.w;
                        C[ms][jt] = acc;
                    }
                }
                #pragma unroll
                for (int ms = 0; ms < 2; ++ms) {
                    const int mt = pr * 2 + ms;
                    float tv[8];
                    #pragma unroll
                    for (int jj = 0; jj < 8; ++jj) {
                        int sl = r + q1 * 32 + (jj >> 2) * 16;
                        float f0 = __shfl(C[ms][0][jj & 3], sl);
                        float f1 = __shfl(C[ms][1][jj & 3], sl);
                        tv[jj] = (qd < 2) ? f0 : f1;
                    }
                    bf16x8 fr = {(bf16)tv[0],(bf16)tv[1],(bf16)tv[2],(bf16)tv[3],
                                 (bf16)tv[4],(bf16)tv[5],(bf16)tv[6],(bf16)tv[7]};
                    if (kind == 0) qB[mt] = fr; else kA[mt] = fr;
                }
            }
            // V: C-tiles -> packed vT LDS writes
            #pragma unroll
            for (int jt = 0; jt < 2; ++jt) {
                const int j0 = 256 + h * 32 + jt * 16;
                const bf16* pw = w_in_b + (size_t)(j0 + r) * 128 + qd * 8;
                bf16x8 wb[4];
                #pragma unroll
                for (int ks = 0; ks < 4; ++ks)
                    wb[ks] = *(const bf16x8*)(pw + ks * 32);
                const float bv = b_in[j0 + r];
                #pragma unroll
                for (int ms = 0; ms < 2; ++ms) {
                    const int mt = pr * 2 + ms;
                    if (mt < mtc) {
                        f32x4 acc = {0.f,0.f,0.f,0.f};
                        #pragma unroll
                        for (int ks = 0; ks < 4; ++ks)
                            acc = __builtin_amdgcn_mfma_f32_16x16x32_bf16(xa[ms][ks], wb[ks], acc, 0, 0, 0);
                        const int rowd = jt * 16 + r;
                        const int uu = (mt * 2 + qh) ^ (rowd & 7);
                        bf16x4 pk = {(bf16)(acc[0]+bv), (bf16)(acc[1]+bv),
                                     (bf16)(acc[2]+bv), (bf16)(acc[3]+bv)};
                        *(bf16x4*)(mylds + rowd * 64 + uu * 8 + q1 * 4) = pk;
                    }
                }
            }
        }

    // ---- preload V^T A-frags (wave-private LDS, no barrier needed) ----
    bf16x8 vf[2][2];
    #pragma unroll
    for (int dt = 0; dt < 2; ++dt)
        #pragma unroll
        for (int hk = 0; hk < 2; ++hk) {
            int row = dt * 16 + r;
            vf[dt][hk] = *(const bf16x8*)(mylds + row * 64 + ((hk * 4 + qd) ^ (row & 7)) * 8);
        }

    const float scale = 0.17677669529663687f;    // 1/sqrt(32)
    const int hkc = (mtc + 1) >> 1;

    // ---- stage 2: per query-tile: S^T -> softmax -> P^T(shuffle) -> PV ----
    #pragma unroll
    for (int mt = 0; mt < 4; ++mt)
        if (mt < mtc) {
            f32x4 S[4];
            #pragma unroll
            for (int nt = 0; nt < 4; ++nt)
                if (nt < mtc) {
                    f32x4 z = {0.f,0.f,0.f,0.f};
                    S[nt] = __builtin_amdgcn_mfma_f32_16x16x32_bf16(kA[nt], qB[mt], z, 0, 0, 0);
                }
            // masked softmax over keys n = nt*16 + qd*4 + i (cross-quad reduce)
            float mx = NEG_INF;
            #pragma unroll
            for (int nt = 0; nt < 4; ++nt) {
                if (nt < mtc) {
                    #pragma unroll
                    for (int i = 0; i < 4; ++i) {
                        bool kv = (nt * 16 + qd * 4 + i) < nb;
                        float val = kv ? S[nt][i] * scale : NEG_INF;
                        S[nt][i] = val;
                        mx = fmaxf(mx, val);
                    }
                } else {
                    S[nt] = (f32x4){NEG_INF, NEG_INF, NEG_INF, NEG_INF};
                }
            }
            mx = fmaxf(mx, __shfl_xor(mx, 16));
            mx = fmaxf(mx, __shfl_xor(mx, 32));
            float l = 0.f;
            #pragma unroll
            for (int nt = 0; nt < 4; ++nt)
                #pragma unroll
                for (int i = 0; i < 4; ++i) {
                    float e = __expf(S[nt][i] - mx);
                    S[nt][i] = e; l += e;
                }
            l += __shfl_xor(l, 16);
            l += __shfl_xor(l, 32);
            const float rl = 1.0f / l;
            #pragma unroll
            for (int nt = 0; nt < 4; ++nt)
                #pragma unroll
                for (int i = 0; i < 4; ++i)
                    S[nt][i] *= rl;                       // invalid keys -> exact 0

            // PV: O^T = V^T * P^T ; P^T frag via quad-shuffle from S^T C-tiles
            f32x4 o0 = {0.f,0.f,0.f,0.f}, o1 = {0.f,0.f,0.f,0.f};
            #pragma unroll
            for (int hk = 0; hk < 2; ++hk)
                if (hk < hkc) {
                    float pv[8];
                    #pragma unroll
                    for (int jj = 0; jj < 8; ++jj) {
                        int sl = r + q1 * 32 + (jj >> 2) * 16;
                        float f0 = __shfl(S[2*hk  ][jj & 3], sl);
                        float f1 = __shfl(S[2*hk+1][jj & 3], sl);
                        pv[jj] = (qd < 2) ? f0 : f1;
                    }
                    bf16x8 pf = {(bf16)pv[0],(bf16)pv[1],(bf16)pv[2],(bf16)pv[3],
                                 (bf16)pv[4],(bf16)pv[5],(bf16)pv[6],(bf16)pv[7]};
                    o0 = __builtin_amdgcn_mfma_f32_16x16x32_bf16(vf[0][hk], pf, o0, 0, 0, 0);
                    o1 = __builtin_amdgcn_mfma_f32_16x16x32_bf16(vf[1][hk], pf, o1, 0, 0, 0);
                }

            // ctx^T B-frag via quad-shuffle -> one b128 write (overlays vT)
            float cv[8];
            #pragma unroll
            for (int jj = 0; jj < 8; ++jj) {
                int sl = r + q1 * 32 + (jj >> 2) * 16;
                float f0 = __shfl(o0[jj & 3], sl);
                float f1 = __shfl(o1[jj & 3], sl);
                cv[jj] = (qd < 2) ? f0 : f1;
            }
            bf16x8 cf = {(bf16)cv[0],(bf16)cv[1],(bf16)cv[2],(bf16)cv[3],
                         (bf16)cv[4],(bf16)cv[5],(bf16)cv[6],(bf16)cv[7]};
            *(bf16x8*)(mylds + mt * 512 + lane * 8) = cf;
        }

    // ---- stage 3 weights (issue before barrier to overlap the wait) ----
    bf16x8 wof[2][4]; float4 bo4[2];
    #pragma unroll
    for (int t2 = 0; t2 < 2; ++t2) {
        const int jg = (w * 2 + t2) * 16;
        const bf16* pw = w_out_b + (size_t)(jg + r) * 128 + qd * 8;
        #pragma unroll
        for (int s = 0; s < 4; ++s)
            wof[t2][s] = *(const bf16x8*)(pw + s * 32);
        bo4[t2] = *(const float4*)(b_out + jg + qd * 4);
    }
    __syncthreads();

    // ---- stage 3: out^T = W_out * ctx^T ; float4 stores ----
    #pragma unroll
    for (int mt = 0; mt < 4; ++mt)
        if (mt < mtc) {
            bf16x8 cb[4];
            #pragma unroll
            for (int s = 0; s < 4; ++s)
                cb[s] = *(const bf16x8*)(s_lds + s * 2048 + mt * 512 + lane * 8);
            const int rowa = mt * 16 + r;
            #pragma unroll
            for (int t2 = 0; t2 < 2; ++t2) {
                f32x4 acc = {0.f,0.f,0.f,0.f};
                #pragma unroll
                for (int s = 0; s < 4; ++s)
                    acc = __builtin_amdgcn_mfma_f32_16x16x32_bf16(wof[t2][s], cb[s], acc, 0, 0, 0);
                if (rowa < nb) {
                    float4 o4 = make_float4(acc[0] + bo4[t2].x, acc[1] + bo4[t2].y,
                                            acc[2] + bo4[t2].z, acc[3] + bo4[t2].w);
                    *(float4*)(out + ((size_t)scene * 64 + rowa) * 128
                               + (w * 2 + t2) * 16 + qd * 4) = o4;
                }
            }
        }
}

extern "C" void kernel_launch(void* const* d_in, const int* in_sizes, int n_in,
                              void* d_out, int out_size, void* d_ws, size_t ws_size,
                              hipStream_t stream)
{
    const float* att_in = (const float*)d_in[0];
    const float* w_in   = (const float*)d_in[1];
    const float* b_in   = (const float*)d_in[2];
    const float* w_out  = (const float*)d_in[3];
    const float* b_out  = (const float*)d_in[4];
    const int*   agents = (const int*)d_in[5];

    bf16* w_in_b  = (bf16*)d_ws;                          // 49152 * 2B
    bf16* w_out_b = w_in_b + 49152;                       // 16384 * 2B
    int*  offs    = (int*)((char*)d_ws + 131072);         // 2048 * 4B
    int*  perm    = (int*)((char*)d_ws + 131072 + 8192);  // 2048 * 4B

    prep_kernel<<<65, 256, 0, stream>>>(w_in, w_out, agents, w_in_b, w_out_b, offs, perm);
    attn_kernel<<<N_SCENES, 256, 0, stream>>>(att_in, b_in, b_out, w_in_b, w_out_b,
                                              agents, offs, perm, (float*)d_out);
}